// Round 10
// baseline (239.153 us; speedup 1.0000x reference)
//
#include <hip/hip_runtime.h>
#include <math.h>

// Problem constants: ALPHA=0.5, MAX_COEFF=10, SHARPNESS=5
// N_VARS=1e6, N_CLAUSES=4e6, N_EDGES=12e6

constexpr int   N_CLAUSES_C = 4000000;
constexpr int   BKT_SHIFT   = 12;                                        // 4096 clauses / bucket
constexpr int   BKT_CLS     = 1 << BKT_SHIFT;
constexpr int   NB_TOTAL    = (N_CLAUSES_C + BKT_CLS - 1) >> BKT_SHIFT;  // 977
constexpr int   CAP         = 13056;   // mean 12288, sd ~111; ~7 sigma, mult of 4
constexpr int   SC_THREADS  = 1024;
constexpr int   SC_WAVES    = SC_THREADS / 64;
constexpr int   BATCH       = 8192;    // 8 edges/thread; runs ~8.4 words >= 32B
constexpr int   NBATCH      = 3;
constexpr int   SC_CHUNK    = BATCH * NBATCH;   // 24576 -> 489 blocks
constexpr int   PR_THREADS  = 512;

typedef int v4i __attribute__((ext_vector_type(4)));

// ev encoding: top-20-bits-of-f32, round-to-nearest. RELATIVE err <= 2^-13 at
// every magnitude (linear quant zeroed tiny ev -> cv=den/nom exploded to inf).
// Exact for 0 and monotone; ev<=1.0 -> 0x7F000 < 2^20.
__device__ __forceinline__ uint32_t ev_enc(float ev) {
    return (__float_as_uint(ev) + 0x400u) >> 11;
}
__device__ __forceinline__ float ev_dec(uint32_t q) {
    return __uint_as_float(q << 11);
}

// Phase A: per-batch histogram+scan -> claim per-bucket global runs -> LDS
// reorder -> per-wave per-bucket coalesced write-out (no bufB: LDS ~44 KB ->
// 2 blocks/CU = 32 waves = full residency, with BATCH=8192 runs >= 32B).
__global__ __launch_bounds__(SC_THREADS) void
scatter_kernel(const float* __restrict__ vp,
               const int* __restrict__ lits,
               const int* __restrict__ cls,
               const int* __restrict__ efi,     // ef as int bits (sign = -1)
               uint32_t* __restrict__ payload,  // [nbp][CAP]
               uint32_t* __restrict__ cursors,  // [NB_TOTAL], zeroed
               int n_edges, int b_lo, int b_hi) {
    __shared__ uint32_t bh[NB_TOTAL];     // per-batch histogram (counts persist)
    __shared__ uint32_t bOff[NB_TOTAL];   // per-batch exclusive scan (LDS base)
    __shared__ uint32_t bb[NB_TOTAL];     // per-batch claimed global base
    __shared__ uint32_t buf[BATCH];       // staged packed entries (32 KB)
    __shared__ uint32_t wsums[SC_WAVES];

    const int tid  = threadIdx.x;
    const int lane = tid & 63;
    const int wv   = tid >> 6;
    const int nbp  = b_hi - b_lo;         // <= 977
    const int c0   = blockIdx.x * SC_CHUNK;
    const int c1   = min(n_edges, c0 + SC_CHUNK);

    for (int batch = 0; batch < NBATCH; ++batch) {
        const int ebase = c0 + batch * BATCH;
        if (ebase >= c1) break;            // block-uniform
        for (int i = tid; i < nbp; i += SC_THREADS) bh[i] = 0;
        __syncthreads();

        // vectorized stream loads: 8 consecutive edges per thread
        const int base = ebase + tid * 8;
        int cc[8], ll[8], ss[8];
        if (base + 8 <= c1) {
            v4i ca = __builtin_nontemporal_load((const v4i*)(cls  + base));
            v4i cb = __builtin_nontemporal_load((const v4i*)(cls  + base + 4));
            v4i la = __builtin_nontemporal_load((const v4i*)(lits + base));
            v4i lb = __builtin_nontemporal_load((const v4i*)(lits + base + 4));
            v4i fa = __builtin_nontemporal_load((const v4i*)(efi  + base));
            v4i fb = __builtin_nontemporal_load((const v4i*)(efi  + base + 4));
            #pragma unroll
            for (int i = 0; i < 4; ++i) {
                cc[i] = ca[i]; cc[4 + i] = cb[i];
                ll[i] = la[i]; ll[4 + i] = lb[i];
                ss[i] = fa[i]; ss[4 + i] = fb[i];
            }
        } else {
            #pragma unroll
            for (int i = 0; i < 8; ++i) {
                int e = base + i;
                if (e < c1) { cc[i] = cls[e]; ll[i] = lits[e]; ss[i] = efi[e]; }
                else cc[i] = -1;           // invalid marker (clause ids >= 0)
            }
        }

        // issue all 8 vp gathers (independent; overlap with ranking below)
        float vv[8];
        #pragma unroll
        for (int i = 0; i < 8; ++i) vv[i] = (cc[i] >= 0) ? vp[ll[i]] : 0.0f;

        // rank: needs cls only (gathers still in flight)
        uint16_t ebk[8], ern[8];
        #pragma unroll
        for (int i = 0; i < 8; ++i) {
            ebk[i] = 0xFFFFu;
            if (cc[i] >= 0) {
                int b = cc[i] >> BKT_SHIFT;
                if (b >= b_lo && b < b_hi) {
                    int ib = b - b_lo;
                    ebk[i] = (uint16_t)ib;
                    ern[i] = (uint16_t)atomicAdd(&bh[ib], 1u);
                }
            }
        }
        // packed entry: ev select (f=+1 -> vp, f=-1 -> 1-vp; exact)
        uint32_t ent[8];
        #pragma unroll
        for (int i = 0; i < 8; ++i) {
            if (ebk[i] != 0xFFFFu) {
                float ev = (ss[i] >= 0) ? vv[i] : (1.0f - vv[i]);
                ent[i] = (ev_enc(ev) << BKT_SHIFT) | (uint32_t)(cc[i] & (BKT_CLS - 1));
            }
        }
        __syncthreads();

        // exclusive scan of bh -> bOff; claim global runs -> bb (counts stay in bh)
        uint32_t v = (tid < nbp) ? bh[tid] : 0u;
        uint32_t x = v;
        #pragma unroll
        for (int d = 1; d < 64; d <<= 1) {
            uint32_t n = __shfl_up(x, (unsigned)d, 64);
            if (lane >= d) x += n;
        }
        if (lane == 63) wsums[wv] = x;
        __syncthreads();
        if (tid == 0) {
            uint32_t r = 0;
            #pragma unroll
            for (int w = 0; w < SC_WAVES; ++w) { uint32_t tm = wsums[w]; wsums[w] = r; r += tm; }
        }
        __syncthreads();
        if (tid < nbp) {
            bOff[tid] = (x - v) + wsums[wv];
            bb[tid]   = v ? atomicAdd(&cursors[b_lo + tid], v) : 0u;
        }
        __syncthreads();

        // stage into bucket-grouped LDS
        #pragma unroll
        for (int i = 0; i < 8; ++i) {
            if (ebk[i] != 0xFFFFu)
                buf[bOff[ebk[i]] + ern[i]] = ent[i];
        }
        __syncthreads();

        // per-wave per-bucket coalesced write-out (no per-slot bucket array)
        for (int ib = wv; ib < nbp; ib += SC_WAVES) {
            uint32_t cntb = bh[ib];
            if (!cntb) continue;
            uint32_t sb = bOff[ib];
            uint32_t gb = bb[ib];
            uint32_t* dst = payload + (size_t)ib * CAP;
            for (uint32_t k = lane; k < cntb; k += 64) {
                uint32_t gpos = gb + k;
                if (gpos < (uint32_t)CAP) dst[gpos] = buf[sb + k];
            }
        }
        __syncthreads();   // protect bh re-zero next batch
    }
}

// Phase B: one block per bucket. Counting-sort by clause (u32 LDS atomics
// ONLY), then per-thread register accumulation — no fp atomics anywhere.
__global__ __launch_bounds__(PR_THREADS) void
process_kernel(const uint32_t* __restrict__ payload,
               const uint32_t* __restrict__ cursors,
               const float* __restrict__ gstep,
               const float* __restrict__ epsp,
               double* __restrict__ acc,
               int b_lo) {
    __shared__ uint32_t offp[BKT_CLS / 2];   // 2 u16 counts per word, 8 KB
    __shared__ uint32_t srt[CAP];            // 52.2 KB
    __shared__ uint32_t wscan[8];
    __shared__ double   wsum[8];
    const int tid  = threadIdx.x;
    const int lane = tid & 63;
    const int wv   = tid >> 6;
    const int b    = b_lo + blockIdx.x;

    for (int j = tid; j < BKT_CLS / 2; j += PR_THREADS) offp[j] = 0;
    __syncthreads();

    const uint32_t cnt = min(cursors[b], (uint32_t)CAP);
    const uint32_t* pl = payload + (size_t)blockIdx.x * CAP;
    const uint32_t nv = cnt >> 2;

    // pass 1: clause histogram (packed u16 halves; counts < 2^16)
    for (uint32_t k = tid; k < nv; k += PR_THREADS) {
        uint4 p4 = ((const uint4*)pl)[k];
        uint32_t c;
        c = p4.x & (BKT_CLS - 1); atomicAdd(&offp[c >> 1], 1u << ((c & 1) << 4));
        c = p4.y & (BKT_CLS - 1); atomicAdd(&offp[c >> 1], 1u << ((c & 1) << 4));
        c = p4.z & (BKT_CLS - 1); atomicAdd(&offp[c >> 1], 1u << ((c & 1) << 4));
        c = p4.w & (BKT_CLS - 1); atomicAdd(&offp[c >> 1], 1u << ((c & 1) << 4));
    }
    for (uint32_t k = (nv << 2) + tid; k < cnt; k += PR_THREADS) {
        uint32_t c = pl[k] & (BKT_CLS - 1);
        atomicAdd(&offp[c >> 1], 1u << ((c & 1) << 4));
    }
    __syncthreads();

    // in-place exclusive scan of 4096 packed-u16 counts (thread owns 4 words)
    uint32_t pk[4];
    const int jb = tid * 4;
    uint32_t t = 0;
    #pragma unroll
    for (int i = 0; i < 4; ++i) {
        pk[i] = offp[jb + i];
        t += (pk[i] & 0xFFFFu) + (pk[i] >> 16);
    }
    uint32_t x = t;
    #pragma unroll
    for (int d = 1; d < 64; d <<= 1) {
        uint32_t n = __shfl_up(x, (unsigned)d, 64);
        if (lane >= d) x += n;
    }
    if (lane == 63) wscan[wv] = x;
    __syncthreads();
    if (tid == 0) {
        uint32_t r = 0;
        #pragma unroll
        for (int w = 0; w < 8; ++w) { uint32_t tm = wscan[w]; wscan[w] = r; r += tm; }
    }
    __syncthreads();
    uint32_t run = (x - t) + wscan[wv];
    #pragma unroll
    for (int i = 0; i < 4; ++i) {
        uint32_t lo = pk[i] & 0xFFFFu, hi = pk[i] >> 16;
        offp[jb + i] = run | ((run + lo) << 16);   // both starts <= cnt < 2^16
        run += lo + hi;
    }
    __syncthreads();

    // pass 2: place entries clause-sorted (ds_add_rtn_u32 rank)
    for (uint32_t k = tid; k < nv; k += PR_THREADS) {
        uint4 p4 = ((const uint4*)pl)[k];
        #pragma unroll
        for (int j = 0; j < 4; ++j) {
            uint32_t p = (j == 0) ? p4.x : (j == 1) ? p4.y : (j == 2) ? p4.z : p4.w;
            uint32_t c = p & (BKT_CLS - 1);
            uint32_t sh = (c & 1) << 4;
            uint32_t r = atomicAdd(&offp[c >> 1], 1u << sh);
            srt[(r >> sh) & 0xFFFFu] = p;
        }
    }
    for (uint32_t k = (nv << 2) + tid; k < cnt; k += PR_THREADS) {
        uint32_t p = pl[k];
        uint32_t c = p & (BKT_CLS - 1);
        uint32_t sh = (c & 1) << 4;
        uint32_t r = atomicAdd(&offp[c >> 1], 1u << sh);
        srt[(r >> sh) & 0xFFFFu] = p;
    }
    __syncthreads();
    // offp half j == END of segment j; start(j) = end(j-1), start(0)=0

    // pass 3: per-clause register accumulation + log epilogue
    const float coeff = fminf(sqrtf(gstep[0]), 10.0f);
    const float eps   = epsp[0];
    const int gbase = b << BKT_SHIFT;
    double local = 0.0;
    for (int j = tid; j < BKT_CLS; j += PR_THREADS) {
        if (gbase + j < N_CLAUSES_C) {
            uint32_t e = (offp[j >> 1] >> ((j & 1) << 4)) & 0xFFFFu;
            uint32_t s = 0;
            if (j > 0) {
                int jm = j - 1;
                s = (offp[jm >> 1] >> ((jm & 1) << 4)) & 0xFFFFu;
            }
            float nom = 0.f, den = 0.f;
            for (uint32_t k = s; k < e; ++k) {
                float ev = ev_dec(srt[k] >> BKT_SHIFT);
                float w  = __expf(coeff * ev);
                nom = fmaf(w, ev, nom);
                den += w;
            }
            float cv = den / fmaxf(nom, eps);   // empty clause: 0/eps = 0 (ref-match)
            float tt = cv - 1.0f;
            float t2 = tt * tt;
            float cv2 = 1.0f + t2 * t2 * tt;    // 1 + (cv-1)^5
            local += (double)__logf(fmaxf(cv2, eps));
        }
    }
    #pragma unroll
    for (int off = 32; off > 0; off >>= 1) local += __shfl_down(local, off, 64);
    if (lane == 0) wsum[wv] = local;
    __syncthreads();
    if (tid == 0) {
        double s = 0.0;
        #pragma unroll
        for (int w = 0; w < 8; ++w) s += wsum[w];
        unsafeAtomicAdd(acc, s);
    }
}

__global__ void finalize_kernel(const double* __restrict__ acc,
                                const int* __restrict__ ncp,
                                float* __restrict__ out) {
    if (threadIdx.x == 0 && blockIdx.x == 0)
        out[0] = (float)(acc[0] / (double)ncp[0]);
}

extern "C" void kernel_launch(void* const* d_in, const int* in_sizes, int n_in,
                              void* d_out, int out_size, void* d_ws, size_t ws_size,
                              hipStream_t stream) {
    const float* vp    = (const float*)d_in[0];
    const int*   gmap  = (const int*)d_in[1];
    const float* ef    = (const float*)d_in[2];
    const int*   ncp   = (const int*)d_in[3];
    const float* gstep = (const float*)d_in[4];
    const float* epsp  = (const float*)d_in[5];
    float*       out   = (float*)d_out;

    const int n_edges = in_sizes[1] / 2;
    const int* lits = gmap;
    const int* cls  = gmap + n_edges;

    // choose pass count so payload fits the workspace (P=1 needs ~51MB)
    int P = 8;
    int nbp_max = (NB_TOTAL + 7) / 8;
    size_t cursors_off_w = (size_t)nbp_max * CAP;
    size_t acc_off_w = (cursors_off_w + NB_TOTAL + 1) & ~(size_t)1;
    const int cands[4] = {1, 2, 4, 8};
    for (int ci = 0; ci < 4; ++ci) {
        int cand = cands[ci];
        int nm = (NB_TOTAL + cand - 1) / cand;
        size_t pw = (size_t)nm * CAP;
        size_t cw = pw + NB_TOTAL;
        size_t aw = (cw + 1) & ~(size_t)1;
        size_t need = aw * 4 + 8;
        if (need <= ws_size) { P = cand; nbp_max = nm; cursors_off_w = pw; acc_off_w = aw; break; }
    }

    uint32_t* payload = (uint32_t*)d_ws;
    uint32_t* cursors = payload + cursors_off_w;
    double*   acc     = (double*)((uint32_t*)d_ws + acc_off_w);

    // zero cursors + accumulator every call (ws is poisoned, not re-zeroed)
    hipMemsetAsync(cursors, 0, (acc_off_w - cursors_off_w) * 4 + 8, stream);

    const int sc_blocks = (n_edges + SC_CHUNK - 1) / SC_CHUNK;  // 489 for 12M
    for (int p = 0; p < P; ++p) {
        int b_lo = p * nbp_max;
        int b_hi = min(NB_TOTAL, b_lo + nbp_max);
        if (b_lo >= b_hi) continue;
        scatter_kernel<<<sc_blocks, SC_THREADS, 0, stream>>>(
            vp, lits, cls, (const int*)ef, payload, cursors, n_edges, b_lo, b_hi);
        process_kernel<<<b_hi - b_lo, PR_THREADS, 0, stream>>>(
            payload, cursors, gstep, epsp, acc, b_lo);
    }
    finalize_kernel<<<1, 64, 0, stream>>>(acc, ncp, out);
}

// Round 11
// 179.451 us; speedup vs baseline: 1.3327x; 1.3327x over previous
//
#include <hip/hip_runtime.h>
#include <math.h>

// Problem constants: ALPHA=0.5, MAX_COEFF=10, SHARPNESS=5
// N_VARS=1e6, N_CLAUSES=4e6, N_EDGES=12e6

constexpr int   N_CLAUSES_C = 4000000;
constexpr int   BKT_SHIFT   = 12;                                        // 4096 clauses / bucket
constexpr int   BKT_CLS     = 1 << BKT_SHIFT;
constexpr int   NB_TOTAL    = (N_CLAUSES_C + BKT_CLS - 1) >> BKT_SHIFT;  // 977
constexpr int   CAP         = 13056;   // mean 12288, sd ~111; ~7 sigma, mult of 4
constexpr int   SC_THREADS  = 1024;
constexpr int   BATCH       = 8192;    // runs ~8.4 words >= 32B sectors
constexpr int   NBATCH      = 3;
constexpr int   SC_CHUNK    = BATCH * NBATCH;   // 24576 -> 489 blocks
constexpr int   PR_THREADS  = 512;

typedef int v4i __attribute__((ext_vector_type(4)));

// ev encoding: top-20-bits-of-f32, round-to-nearest. RELATIVE err <= 2^-13 at
// every magnitude (linear quant zeroed tiny ev -> cv=den/nom exploded to inf).
// Exact for 0 and monotone; ev<=1.0 -> 0x7F000 < 2^20.
__device__ __forceinline__ uint32_t ev_enc(float ev) {
    return (__float_as_uint(ev) + 0x400u) >> 11;
}
__device__ __forceinline__ float ev_dec(uint32_t q) {
    return __uint_as_float(q << 11);
}

// Phase A (R8 structure, R9 loads): per-batch histogram via rank atomics ->
// scan -> claim global runs -> stage bucket-grouped in LDS (buf+bufB) ->
// LINEAR coalesced write-out over slots (all 64 lanes active every iter).
__global__ __launch_bounds__(SC_THREADS) void
scatter_kernel(const float* __restrict__ vp,
               const int* __restrict__ lits,
               const int* __restrict__ cls,
               const int* __restrict__ efi,     // ef as int bits (sign = -1)
               uint32_t* __restrict__ payload,  // [nbp][CAP]
               uint32_t* __restrict__ cursors,  // [NB_TOTAL], zeroed
               int n_edges, int b_lo, int b_hi) {
    __shared__ uint32_t bh[NB_TOTAL];     // per-batch histogram / counts
    __shared__ uint32_t bOff[NB_TOTAL];   // per-batch exclusive scan (LDS base)
    __shared__ uint32_t bb[NB_TOTAL];     // per-batch claimed global base
    __shared__ uint32_t buf[BATCH];       // staged packed entries (32 KB)
    __shared__ uint16_t bufB[BATCH];      // staged bucket ids (16 KB)
    __shared__ uint32_t wsums[16];
    __shared__ uint32_t totalS;

    const int tid  = threadIdx.x;
    const int lane = tid & 63;
    const int wv   = tid >> 6;
    const int nbp  = b_hi - b_lo;         // <= 977
    const int c0   = blockIdx.x * SC_CHUNK;
    const int c1   = min(n_edges, c0 + SC_CHUNK);

    for (int batch = 0; batch < NBATCH; ++batch) {
        const int ebase = c0 + batch * BATCH;
        if (ebase >= c1) break;            // block-uniform
        for (int i = tid; i < nbp; i += SC_THREADS) bh[i] = 0;
        __syncthreads();

        // vectorized stream loads: 8 consecutive edges per thread (2x dwordx4 each)
        const int base = ebase + tid * 8;
        int cc[8], ll[8], ss[8];
        if (base + 8 <= c1) {
            v4i ca = __builtin_nontemporal_load((const v4i*)(cls  + base));
            v4i cb = __builtin_nontemporal_load((const v4i*)(cls  + base + 4));
            v4i la = __builtin_nontemporal_load((const v4i*)(lits + base));
            v4i lb = __builtin_nontemporal_load((const v4i*)(lits + base + 4));
            v4i fa = __builtin_nontemporal_load((const v4i*)(efi  + base));
            v4i fb = __builtin_nontemporal_load((const v4i*)(efi  + base + 4));
            #pragma unroll
            for (int i = 0; i < 4; ++i) {
                cc[i] = ca[i]; cc[4 + i] = cb[i];
                ll[i] = la[i]; ll[4 + i] = lb[i];
                ss[i] = fa[i]; ss[4 + i] = fb[i];
            }
        } else {
            #pragma unroll
            for (int i = 0; i < 8; ++i) {
                int e = base + i;
                if (e < c1) { cc[i] = cls[e]; ll[i] = lits[e]; ss[i] = efi[e]; }
                else cc[i] = -1;           // invalid marker (clause ids >= 0)
            }
        }

        // issue all 8 vp gathers (independent; overlap with ranking below)
        float vv[8];
        #pragma unroll
        for (int i = 0; i < 8; ++i) vv[i] = (cc[i] >= 0) ? vp[ll[i]] : 0.0f;

        // rank: needs cls only (gathers still in flight)
        uint16_t ebk[8], ern[8];
        #pragma unroll
        for (int i = 0; i < 8; ++i) {
            ebk[i] = 0xFFFFu;
            if (cc[i] >= 0) {
                int b = cc[i] >> BKT_SHIFT;
                if (b >= b_lo && b < b_hi) {
                    int ib = b - b_lo;
                    ebk[i] = (uint16_t)ib;
                    ern[i] = (uint16_t)atomicAdd(&bh[ib], 1u);
                }
            }
        }
        // packed entry: ev select (f=+1 -> vp, f=-1 -> 1-vp; exact)
        uint32_t ent[8];
        #pragma unroll
        for (int i = 0; i < 8; ++i) {
            if (ebk[i] != 0xFFFFu) {
                float ev = (ss[i] >= 0) ? vv[i] : (1.0f - vv[i]);
                ent[i] = (ev_enc(ev) << BKT_SHIFT) | (uint32_t)(cc[i] & (BKT_CLS - 1));
            }
        }
        __syncthreads();

        // exclusive prefix scan of bh -> bOff; claim global runs -> bb
        uint32_t v = (tid < nbp) ? bh[tid] : 0u;
        uint32_t x = v;
        #pragma unroll
        for (int d = 1; d < 64; d <<= 1) {
            uint32_t n = __shfl_up(x, (unsigned)d, 64);
            if (lane >= d) x += n;
        }
        if (lane == 63) wsums[wv] = x;
        __syncthreads();
        if (tid == 0) {
            uint32_t r = 0;
            #pragma unroll
            for (int w = 0; w < 16; ++w) { uint32_t tm = wsums[w]; wsums[w] = r; r += tm; }
        }
        __syncthreads();
        if (tid < nbp) {
            bOff[tid] = (x - v) + wsums[wv];
            bb[tid]   = v ? atomicAdd(&cursors[b_lo + tid], v) : 0u;
        }
        if (tid == SC_THREADS - 1) totalS = x + wsums[wv];
        __syncthreads();

        // stage into bucket-grouped LDS
        #pragma unroll
        for (int i = 0; i < 8; ++i) {
            if (ebk[i] != 0xFFFFu) {
                uint32_t s = bOff[ebk[i]] + ern[i];
                buf[s]  = ent[i];
                bufB[s] = ebk[i];
            }
        }
        __syncthreads();

        // linear coalesced write-out: all lanes store every iteration
        const uint32_t tS = totalS;
        for (uint32_t s = tid; s < tS; s += SC_THREADS) {
            uint32_t ib   = bufB[s];
            uint32_t gpos = bb[ib] + (s - bOff[ib]);
            if (gpos < (uint32_t)CAP)
                payload[(size_t)ib * CAP + gpos] = buf[s];
        }
        __syncthreads();   // protect bh re-zero next batch
    }
}

// Phase B: one block per bucket. Counting-sort by clause (u32 LDS atomics
// ONLY), then per-thread register accumulation — no fp atomics anywhere.
__global__ __launch_bounds__(PR_THREADS) void
process_kernel(const uint32_t* __restrict__ payload,
               const uint32_t* __restrict__ cursors,
               const float* __restrict__ gstep,
               const float* __restrict__ epsp,
               double* __restrict__ acc,
               int b_lo) {
    __shared__ uint32_t offp[BKT_CLS / 2];   // 2 u16 counts per word, 8 KB
    __shared__ uint32_t srt[CAP];            // 52.2 KB
    __shared__ uint32_t wscan[8];
    __shared__ double   wsum[8];
    const int tid  = threadIdx.x;
    const int lane = tid & 63;
    const int wv   = tid >> 6;
    const int b    = b_lo + blockIdx.x;

    for (int j = tid; j < BKT_CLS / 2; j += PR_THREADS) offp[j] = 0;
    __syncthreads();

    const uint32_t cnt = min(cursors[b], (uint32_t)CAP);
    const uint32_t* pl = payload + (size_t)blockIdx.x * CAP;
    const uint32_t nv = cnt >> 2;

    // pass 1: clause histogram (packed u16 halves; counts < 2^16)
    for (uint32_t k = tid; k < nv; k += PR_THREADS) {
        uint4 p4 = ((const uint4*)pl)[k];
        uint32_t c;
        c = p4.x & (BKT_CLS - 1); atomicAdd(&offp[c >> 1], 1u << ((c & 1) << 4));
        c = p4.y & (BKT_CLS - 1); atomicAdd(&offp[c >> 1], 1u << ((c & 1) << 4));
        c = p4.z & (BKT_CLS - 1); atomicAdd(&offp[c >> 1], 1u << ((c & 1) << 4));
        c = p4.w & (BKT_CLS - 1); atomicAdd(&offp[c >> 1], 1u << ((c & 1) << 4));
    }
    for (uint32_t k = (nv << 2) + tid; k < cnt; k += PR_THREADS) {
        uint32_t c = pl[k] & (BKT_CLS - 1);
        atomicAdd(&offp[c >> 1], 1u << ((c & 1) << 4));
    }
    __syncthreads();

    // in-place exclusive scan of 4096 packed-u16 counts (thread owns 4 words)
    uint32_t pk[4];
    const int jb = tid * 4;
    uint32_t t = 0;
    #pragma unroll
    for (int i = 0; i < 4; ++i) {
        pk[i] = offp[jb + i];
        t += (pk[i] & 0xFFFFu) + (pk[i] >> 16);
    }
    uint32_t x = t;
    #pragma unroll
    for (int d = 1; d < 64; d <<= 1) {
        uint32_t n = __shfl_up(x, (unsigned)d, 64);
        if (lane >= d) x += n;
    }
    if (lane == 63) wscan[wv] = x;
    __syncthreads();
    if (tid == 0) {
        uint32_t r = 0;
        #pragma unroll
        for (int w = 0; w < 8; ++w) { uint32_t tm = wscan[w]; wscan[w] = r; r += tm; }
    }
    __syncthreads();
    uint32_t run = (x - t) + wscan[wv];
    #pragma unroll
    for (int i = 0; i < 4; ++i) {
        uint32_t lo = pk[i] & 0xFFFFu, hi = pk[i] >> 16;
        offp[jb + i] = run | ((run + lo) << 16);   // both starts <= cnt < 2^16
        run += lo + hi;
    }
    __syncthreads();

    // pass 2: place entries clause-sorted (ds_add_rtn_u32 rank)
    for (uint32_t k = tid; k < nv; k += PR_THREADS) {
        uint4 p4 = ((const uint4*)pl)[k];
        #pragma unroll
        for (int j = 0; j < 4; ++j) {
            uint32_t p = (j == 0) ? p4.x : (j == 1) ? p4.y : (j == 2) ? p4.z : p4.w;
            uint32_t c = p & (BKT_CLS - 1);
            uint32_t sh = (c & 1) << 4;
            uint32_t r = atomicAdd(&offp[c >> 1], 1u << sh);
            srt[(r >> sh) & 0xFFFFu] = p;
        }
    }
    for (uint32_t k = (nv << 2) + tid; k < cnt; k += PR_THREADS) {
        uint32_t p = pl[k];
        uint32_t c = p & (BKT_CLS - 1);
        uint32_t sh = (c & 1) << 4;
        uint32_t r = atomicAdd(&offp[c >> 1], 1u << sh);
        srt[(r >> sh) & 0xFFFFu] = p;
    }
    __syncthreads();
    // offp half j == END of segment j; start(j) = end(j-1), start(0)=0

    // pass 3: per-clause register accumulation + log epilogue
    const float coeff = fminf(sqrtf(gstep[0]), 10.0f);
    const float eps   = epsp[0];
    const int gbase = b << BKT_SHIFT;
    double local = 0.0;
    for (int j = tid; j < BKT_CLS; j += PR_THREADS) {
        if (gbase + j < N_CLAUSES_C) {
            uint32_t e = (offp[j >> 1] >> ((j & 1) << 4)) & 0xFFFFu;
            uint32_t s = 0;
            if (j > 0) {
                int jm = j - 1;
                s = (offp[jm >> 1] >> ((jm & 1) << 4)) & 0xFFFFu;
            }
            float nom = 0.f, den = 0.f;
            for (uint32_t k = s; k < e; ++k) {
                float ev = ev_dec(srt[k] >> BKT_SHIFT);
                float w  = __expf(coeff * ev);
                nom = fmaf(w, ev, nom);
                den += w;
            }
            float cv = den / fmaxf(nom, eps);   // empty clause: 0/eps = 0 (ref-match)
            float tt = cv - 1.0f;
            float t2 = tt * tt;
            float cv2 = 1.0f + t2 * t2 * tt;    // 1 + (cv-1)^5
            local += (double)__logf(fmaxf(cv2, eps));
        }
    }
    #pragma unroll
    for (int off = 32; off > 0; off >>= 1) local += __shfl_down(local, off, 64);
    if (lane == 0) wsum[wv] = local;
    __syncthreads();
    if (tid == 0) {
        double s = 0.0;
        #pragma unroll
        for (int w = 0; w < 8; ++w) s += wsum[w];
        unsafeAtomicAdd(acc, s);
    }
}

__global__ void finalize_kernel(const double* __restrict__ acc,
                                const int* __restrict__ ncp,
                                float* __restrict__ out) {
    if (threadIdx.x == 0 && blockIdx.x == 0)
        out[0] = (float)(acc[0] / (double)ncp[0]);
}

extern "C" void kernel_launch(void* const* d_in, const int* in_sizes, int n_in,
                              void* d_out, int out_size, void* d_ws, size_t ws_size,
                              hipStream_t stream) {
    const float* vp    = (const float*)d_in[0];
    const int*   gmap  = (const int*)d_in[1];
    const float* ef    = (const float*)d_in[2];
    const int*   ncp   = (const int*)d_in[3];
    const float* gstep = (const float*)d_in[4];
    const float* epsp  = (const float*)d_in[5];
    float*       out   = (float*)d_out;

    const int n_edges = in_sizes[1] / 2;
    const int* lits = gmap;
    const int* cls  = gmap + n_edges;

    // choose pass count so payload fits the workspace (P=1 needs ~51MB)
    int P = 8;
    int nbp_max = (NB_TOTAL + 7) / 8;
    size_t cursors_off_w = (size_t)nbp_max * CAP;
    size_t acc_off_w = (cursors_off_w + NB_TOTAL + 1) & ~(size_t)1;
    const int cands[4] = {1, 2, 4, 8};
    for (int ci = 0; ci < 4; ++ci) {
        int cand = cands[ci];
        int nm = (NB_TOTAL + cand - 1) / cand;
        size_t pw = (size_t)nm * CAP;
        size_t cw = pw + NB_TOTAL;
        size_t aw = (cw + 1) & ~(size_t)1;
        size_t need = aw * 4 + 8;
        if (need <= ws_size) { P = cand; nbp_max = nm; cursors_off_w = pw; acc_off_w = aw; break; }
    }

    uint32_t* payload = (uint32_t*)d_ws;
    uint32_t* cursors = payload + cursors_off_w;
    double*   acc     = (double*)((uint32_t*)d_ws + acc_off_w);

    // zero cursors + accumulator every call (ws is poisoned, not re-zeroed)
    hipMemsetAsync(cursors, 0, (acc_off_w - cursors_off_w) * 4 + 8, stream);

    const int sc_blocks = (n_edges + SC_CHUNK - 1) / SC_CHUNK;  // 489 for 12M
    for (int p = 0; p < P; ++p) {
        int b_lo = p * nbp_max;
        int b_hi = min(NB_TOTAL, b_lo + nbp_max);
        if (b_lo >= b_hi) continue;
        scatter_kernel<<<sc_blocks, SC_THREADS, 0, stream>>>(
            vp, lits, cls, (const int*)ef, payload, cursors, n_edges, b_lo, b_hi);
        process_kernel<<<b_hi - b_lo, PR_THREADS, 0, stream>>>(
            payload, cursors, gstep, epsp, acc, b_lo);
    }
    finalize_kernel<<<1, 64, 0, stream>>>(acc, ncp, out);
}

// Round 12
// 175.232 us; speedup vs baseline: 1.3648x; 1.0241x over previous
//
#include <hip/hip_runtime.h>
#include <math.h>

// Problem constants: ALPHA=0.5, MAX_COEFF=10, SHARPNESS=5
// N_VARS=1e6, N_CLAUSES=4e6, N_EDGES=12e6

constexpr int   N_CLAUSES_C = 4000000;
constexpr int   BKT_SHIFT   = 12;                                        // 4096 clauses / bucket
constexpr int   BKT_CLS     = 1 << BKT_SHIFT;
constexpr int   NB_TOTAL    = (N_CLAUSES_C + BKT_CLS - 1) >> BKT_SHIFT;  // 977
constexpr int   CAP         = 13056;   // mean 12288, sd ~111; ~7 sigma, mult of 4
constexpr int   SC_THREADS  = 1024;
constexpr int   BATCH       = 8192;    // runs ~8.4 words >= 32B sectors
constexpr int   NBATCH      = 3;
constexpr int   SC_CHUNK    = BATCH * NBATCH;   // 24576 -> 489 blocks
constexpr int   PR_THREADS  = 512;

typedef int v4i __attribute__((ext_vector_type(4)));

// ev encoding: top-20-bits-of-f32, round-to-nearest. RELATIVE err <= 2^-13 at
// every magnitude (linear quant zeroed tiny ev -> cv=den/nom exploded to inf).
// Exact for 0 and monotone; ev<=1.0 -> 0x7F000 < 2^20.
__device__ __forceinline__ uint32_t ev_enc(float ev) {
    return (__float_as_uint(ev) + 0x400u) >> 11;
}
__device__ __forceinline__ float ev_dec(uint32_t q) {
    return __uint_as_float(q << 11);
}

__device__ __forceinline__ void load_pair(const int* __restrict__ cls,
                                          const int* __restrict__ lits,
                                          int base, int c1, int (&cc)[8], int (&ll)[8]) {
    if (base + 8 <= c1) {
        v4i ca = __builtin_nontemporal_load((const v4i*)(cls  + base));
        v4i cb = __builtin_nontemporal_load((const v4i*)(cls  + base + 4));
        v4i la = __builtin_nontemporal_load((const v4i*)(lits + base));
        v4i lb = __builtin_nontemporal_load((const v4i*)(lits + base + 4));
        #pragma unroll
        for (int i = 0; i < 4; ++i) {
            cc[i] = ca[i]; cc[4 + i] = cb[i];
            ll[i] = la[i]; ll[4 + i] = lb[i];
        }
    } else {
        #pragma unroll
        for (int i = 0; i < 8; ++i) {
            int e = base + i;
            if (e < c1) { cc[i] = cls[e]; ll[i] = lits[e]; }
            else        { cc[i] = -1;     ll[i] = 0;       }
        }
    }
}

__device__ __forceinline__ void load_ef(const int* __restrict__ efi,
                                        int base, int c1, int (&ss)[8]) {
    if (base + 8 <= c1) {
        v4i fa = __builtin_nontemporal_load((const v4i*)(efi + base));
        v4i fb = __builtin_nontemporal_load((const v4i*)(efi + base + 4));
        #pragma unroll
        for (int i = 0; i < 4; ++i) { ss[i] = fa[i]; ss[4 + i] = fb[i]; }
    } else {
        #pragma unroll
        for (int i = 0; i < 8; ++i) { int e = base + i; ss[i] = (e < c1) ? efi[e] : 0; }
    }
}

// Phase A: 4-barrier pipelined batches.
//   [cc,ll prefetched] -> issue ef+gathers -> rank -> B1
//   -> wave0: full scan | waves1-15: claim bb -> B2
//   -> stage + zero bh + prefetch next cc,ll -> B3 -> write-out -> B4
__global__ __launch_bounds__(SC_THREADS, 8) void
scatter_kernel(const float* __restrict__ vp,
               const int* __restrict__ lits,
               const int* __restrict__ cls,
               const int* __restrict__ efi,     // ef as int bits (sign = -1)
               uint32_t* __restrict__ payload,  // [nbp][CAP]
               uint32_t* __restrict__ cursors,  // [NB_TOTAL], zeroed
               int n_edges, int b_lo, int b_hi) {
    __shared__ uint32_t bh[1024];         // padded histogram (zero-padded tail)
    __shared__ uint32_t bOff[1024];       // exclusive scan of bh (LDS base)
    __shared__ uint32_t bb[NB_TOTAL];     // per-batch claimed global base
    __shared__ uint32_t buf[BATCH];       // staged packed entries (32 KB)
    __shared__ uint16_t bufB[BATCH];      // staged bucket ids (16 KB)
    __shared__ uint32_t totalS;

    const int tid  = threadIdx.x;
    const int lane = tid & 63;
    const int wv   = tid >> 6;
    const int nbp  = b_hi - b_lo;         // <= 977
    const int c0   = blockIdx.x * SC_CHUNK;
    const int c1   = min(n_edges, c0 + SC_CHUNK);
    const int nb   = (c1 - c0 + BATCH - 1) / BATCH;   // block-uniform

    // prologue: batch-0 streams in flight while bh zeroes
    int cc[8], ll[8];
    load_pair(cls, lits, c0 + tid * 8, c1, cc, ll);
    bh[tid] = 0;
    __syncthreads();

    for (int k = 0; k < nb; ++k) {
        const int base = c0 + k * BATCH + tid * 8;

        // issue ef loads + all 8 vp gathers (overlap rank/scan below)
        int ss[8];
        load_ef(efi, base, c1, ss);
        float vv[8];
        #pragma unroll
        for (int i = 0; i < 8; ++i) vv[i] = (cc[i] >= 0) ? vp[ll[i]] : 0.0f;

        // rank (needs cc only); pack (entlo | ern<<12 | ib<<22)
        uint32_t meta[8];
        #pragma unroll
        for (int i = 0; i < 8; ++i) {
            meta[i] = 0xFFC00000u;                 // ib=1023 -> invalid
            if (cc[i] >= 0) {
                int b = cc[i] >> BKT_SHIFT;
                if (b >= b_lo && b < b_hi) {
                    uint32_t ib = (uint32_t)(b - b_lo);
                    uint32_t r  = atomicAdd(&bh[ib], 1u);
                    if (r < 1024u)
                        meta[i] = ((uint32_t)cc[i] & 4095u) | (r << 12) | (ib << 22);
                }
            }
        }
        __syncthreads();                           // B1

        if (wv == 0) {
            // single-wave exclusive scan: 16 contiguous elems/lane, two-pass
            const int jb = lane * 16;
            uint32_t t = 0;
            #pragma unroll
            for (int i = 0; i < 16; ++i) t += bh[jb + i];
            uint32_t x = t;
            #pragma unroll
            for (int d = 1; d < 64; d <<= 1) {
                uint32_t n = __shfl_up(x, (unsigned)d, 64);
                if (lane >= d) x += n;
            }
            uint32_t run = x - t;
            #pragma unroll
            for (int i = 0; i < 16; ++i) {
                uint32_t v = bh[jb + i];
                bOff[jb + i] = run;
                run += v;
            }
            if (lane == 63) totalS = x;
        } else {
            // claim global runs concurrently (reads bh only)
            for (int i = tid - 64; i < nbp; i += SC_THREADS - 64) {
                uint32_t v = bh[i];
                bb[i] = v ? atomicAdd(&cursors[b_lo + i], v) : 0u;
            }
        }
        __syncthreads();                           // B2

        // stage into bucket-grouped LDS (ev select: f=+1 -> vp, f=-1 -> 1-vp)
        #pragma unroll
        for (int i = 0; i < 8; ++i) {
            uint32_t ib = meta[i] >> 22;
            if (ib < 1023u) {
                float ev = (ss[i] >= 0) ? vv[i] : (1.0f - vv[i]);
                uint32_t s = bOff[ib] + ((meta[i] >> 12) & 1023u);
                buf[s]  = (ev_enc(ev) << BKT_SHIFT) | (meta[i] & 4095u);
                bufB[s] = (uint16_t)ib;
            }
        }
        bh[tid] = 0;                               // ready for next batch
        if (k + 1 < nb)                            // prefetch next streams
            load_pair(cls, lits, c0 + (k + 1) * BATCH + tid * 8, c1, cc, ll);
        __syncthreads();                           // B3

        // linear coalesced write-out: all lanes store every iteration
        const uint32_t tS = totalS;
        for (uint32_t s = tid; s < tS; s += SC_THREADS) {
            uint32_t ib   = bufB[s];
            uint32_t gpos = bb[ib] + (s - bOff[ib]);
            if (gpos < (uint32_t)CAP)
                payload[(size_t)ib * CAP + gpos] = buf[s];
        }
        __syncthreads();                           // B4
    }
}

// Phase B: one block per bucket. Counting-sort by clause (u32 LDS atomics
// ONLY), then per-thread register accumulation — no fp atomics anywhere.
__global__ __launch_bounds__(PR_THREADS) void
process_kernel(const uint32_t* __restrict__ payload,
               const uint32_t* __restrict__ cursors,
               const float* __restrict__ gstep,
               const float* __restrict__ epsp,
               double* __restrict__ acc,
               int b_lo) {
    __shared__ uint32_t offp[BKT_CLS / 2];   // 2 u16 counts per word, 8 KB
    __shared__ uint32_t srt[CAP];            // 52.2 KB
    __shared__ uint32_t wscan[8];
    __shared__ double   wsum[8];
    const int tid  = threadIdx.x;
    const int lane = tid & 63;
    const int wv   = tid >> 6;
    const int b    = b_lo + blockIdx.x;

    for (int j = tid; j < BKT_CLS / 2; j += PR_THREADS) offp[j] = 0;
    __syncthreads();

    const uint32_t cnt = min(cursors[b], (uint32_t)CAP);
    const uint32_t* pl = payload + (size_t)blockIdx.x * CAP;
    const uint32_t nv = cnt >> 2;

    // pass 1: clause histogram (packed u16 halves; counts < 2^16)
    for (uint32_t k = tid; k < nv; k += PR_THREADS) {
        uint4 p4 = ((const uint4*)pl)[k];
        uint32_t c;
        c = p4.x & (BKT_CLS - 1); atomicAdd(&offp[c >> 1], 1u << ((c & 1) << 4));
        c = p4.y & (BKT_CLS - 1); atomicAdd(&offp[c >> 1], 1u << ((c & 1) << 4));
        c = p4.z & (BKT_CLS - 1); atomicAdd(&offp[c >> 1], 1u << ((c & 1) << 4));
        c = p4.w & (BKT_CLS - 1); atomicAdd(&offp[c >> 1], 1u << ((c & 1) << 4));
    }
    for (uint32_t k = (nv << 2) + tid; k < cnt; k += PR_THREADS) {
        uint32_t c = pl[k] & (BKT_CLS - 1);
        atomicAdd(&offp[c >> 1], 1u << ((c & 1) << 4));
    }
    __syncthreads();

    // in-place exclusive scan of 4096 packed-u16 counts (thread owns 4 words)
    uint32_t pk[4];
    const int jb = tid * 4;
    uint32_t t = 0;
    #pragma unroll
    for (int i = 0; i < 4; ++i) {
        pk[i] = offp[jb + i];
        t += (pk[i] & 0xFFFFu) + (pk[i] >> 16);
    }
    uint32_t x = t;
    #pragma unroll
    for (int d = 1; d < 64; d <<= 1) {
        uint32_t n = __shfl_up(x, (unsigned)d, 64);
        if (lane >= d) x += n;
    }
    if (lane == 63) wscan[wv] = x;
    __syncthreads();
    if (tid == 0) {
        uint32_t r = 0;
        #pragma unroll
        for (int w = 0; w < 8; ++w) { uint32_t tm = wscan[w]; wscan[w] = r; r += tm; }
    }
    __syncthreads();
    uint32_t run = (x - t) + wscan[wv];
    #pragma unroll
    for (int i = 0; i < 4; ++i) {
        uint32_t lo = pk[i] & 0xFFFFu, hi = pk[i] >> 16;
        offp[jb + i] = run | ((run + lo) << 16);   // both starts <= cnt < 2^16
        run += lo + hi;
    }
    __syncthreads();

    // pass 2: place entries clause-sorted (ds_add_rtn_u32 rank)
    for (uint32_t k = tid; k < nv; k += PR_THREADS) {
        uint4 p4 = ((const uint4*)pl)[k];
        #pragma unroll
        for (int j = 0; j < 4; ++j) {
            uint32_t p = (j == 0) ? p4.x : (j == 1) ? p4.y : (j == 2) ? p4.z : p4.w;
            uint32_t c = p & (BKT_CLS - 1);
            uint32_t sh = (c & 1) << 4;
            uint32_t r = atomicAdd(&offp[c >> 1], 1u << sh);
            srt[(r >> sh) & 0xFFFFu] = p;
        }
    }
    for (uint32_t k = (nv << 2) + tid; k < cnt; k += PR_THREADS) {
        uint32_t p = pl[k];
        uint32_t c = p & (BKT_CLS - 1);
        uint32_t sh = (c & 1) << 4;
        uint32_t r = atomicAdd(&offp[c >> 1], 1u << sh);
        srt[(r >> sh) & 0xFFFFu] = p;
    }
    __syncthreads();
    // offp half j == END of segment j; start(j) = end(j-1), start(0)=0

    // pass 3: per-clause register accumulation + log epilogue
    const float coeff = fminf(sqrtf(gstep[0]), 10.0f);
    const float eps   = epsp[0];
    const int gbase = b << BKT_SHIFT;
    double local = 0.0;
    for (int j = tid; j < BKT_CLS; j += PR_THREADS) {
        if (gbase + j < N_CLAUSES_C) {
            uint32_t e = (offp[j >> 1] >> ((j & 1) << 4)) & 0xFFFFu;
            uint32_t s = 0;
            if (j > 0) {
                int jm = j - 1;
                s = (offp[jm >> 1] >> ((jm & 1) << 4)) & 0xFFFFu;
            }
            float nom = 0.f, den = 0.f;
            for (uint32_t k = s; k < e; ++k) {
                float ev = ev_dec(srt[k] >> BKT_SHIFT);
                float w  = __expf(coeff * ev);
                nom = fmaf(w, ev, nom);
                den += w;
            }
            float cv = den / fmaxf(nom, eps);   // empty clause: 0/eps = 0 (ref-match)
            float tt = cv - 1.0f;
            float t2 = tt * tt;
            float cv2 = 1.0f + t2 * t2 * tt;    // 1 + (cv-1)^5
            local += (double)__logf(fmaxf(cv2, eps));
        }
    }
    #pragma unroll
    for (int off = 32; off > 0; off >>= 1) local += __shfl_down(local, off, 64);
    if (lane == 0) wsum[wv] = local;
    __syncthreads();
    if (tid == 0) {
        double s = 0.0;
        #pragma unroll
        for (int w = 0; w < 8; ++w) s += wsum[w];
        unsafeAtomicAdd(acc, s);
    }
}

__global__ void finalize_kernel(const double* __restrict__ acc,
                                const int* __restrict__ ncp,
                                float* __restrict__ out) {
    if (threadIdx.x == 0 && blockIdx.x == 0)
        out[0] = (float)(acc[0] / (double)ncp[0]);
}

extern "C" void kernel_launch(void* const* d_in, const int* in_sizes, int n_in,
                              void* d_out, int out_size, void* d_ws, size_t ws_size,
                              hipStream_t stream) {
    const float* vp    = (const float*)d_in[0];
    const int*   gmap  = (const int*)d_in[1];
    const float* ef    = (const float*)d_in[2];
    const int*   ncp   = (const int*)d_in[3];
    const float* gstep = (const float*)d_in[4];
    const float* epsp  = (const float*)d_in[5];
    float*       out   = (float*)d_out;

    const int n_edges = in_sizes[1] / 2;
    const int* lits = gmap;
    const int* cls  = gmap + n_edges;

    // choose pass count so payload fits the workspace (P=1 needs ~51MB)
    int P = 8;
    int nbp_max = (NB_TOTAL + 7) / 8;
    size_t cursors_off_w = (size_t)nbp_max * CAP;
    size_t acc_off_w = (cursors_off_w + NB_TOTAL + 1) & ~(size_t)1;
    const int cands[4] = {1, 2, 4, 8};
    for (int ci = 0; ci < 4; ++ci) {
        int cand = cands[ci];
        int nm = (NB_TOTAL + cand - 1) / cand;
        size_t pw = (size_t)nm * CAP;
        size_t cw = pw + NB_TOTAL;
        size_t aw = (cw + 1) & ~(size_t)1;
        size_t need = aw * 4 + 8;
        if (need <= ws_size) { P = cand; nbp_max = nm; cursors_off_w = pw; acc_off_w = aw; break; }
    }

    uint32_t* payload = (uint32_t*)d_ws;
    uint32_t* cursors = payload + cursors_off_w;
    double*   acc     = (double*)((uint32_t*)d_ws + acc_off_w);

    // zero cursors + accumulator every call (ws is poisoned, not re-zeroed)
    hipMemsetAsync(cursors, 0, (acc_off_w - cursors_off_w) * 4 + 8, stream);

    const int sc_blocks = (n_edges + SC_CHUNK - 1) / SC_CHUNK;  // 489 for 12M
    for (int p = 0; p < P; ++p) {
        int b_lo = p * nbp_max;
        int b_hi = min(NB_TOTAL, b_lo + nbp_max);
        if (b_lo >= b_hi) continue;
        scatter_kernel<<<sc_blocks, SC_THREADS, 0, stream>>>(
            vp, lits, cls, (const int*)ef, payload, cursors, n_edges, b_lo, b_hi);
        process_kernel<<<b_hi - b_lo, PR_THREADS, 0, stream>>>(
            payload, cursors, gstep, epsp, acc, b_lo);
    }
    finalize_kernel<<<1, 64, 0, stream>>>(acc, ncp, out);
}

// Round 13
// 170.790 us; speedup vs baseline: 1.4003x; 1.0260x over previous
//
#include <hip/hip_runtime.h>
#include <math.h>

// Problem constants: ALPHA=0.5, MAX_COEFF=10, SHARPNESS=5
// N_VARS=1e6, N_CLAUSES=4e6, N_EDGES=12e6

constexpr int   N_CLAUSES_C = 4000000;
constexpr int   BKT_SHIFT   = 13;                                        // 8192 clauses / coarse bucket
constexpr int   BKT_CLS     = 1 << BKT_SHIFT;
constexpr int   NB_TOTAL    = (N_CLAUSES_C + BKT_CLS - 1) >> BKT_SHIFT;  // 489
constexpr int   CAP         = 25728;   // mean 24576, sd ~157; ~7 sigma
constexpr int   SUB_CLS     = 4096;    // process granularity (half a coarse bucket)
constexpr int   SRT_CAP     = 13824;   // sub-bucket mean 12288 + 7 sigma + pad
constexpr int   SC_THREADS  = 1024;
constexpr int   BATCH       = 8192;    // runs ~16.8 words (~67B) with 489 buckets
constexpr int   NBATCH      = 3;
constexpr int   SC_CHUNK    = BATCH * NBATCH;   // 24576 -> 489 blocks
constexpr int   PR_THREADS  = 512;

typedef int v4i __attribute__((ext_vector_type(4)));

// ev encoding: top-19-bits-of-f32 with round-to-nearest. RELATIVE err <= 2^-12
// at every magnitude (linear quant zeroed tiny ev -> cv=den/nom -> inf).
// Exact for 0; monotone; ev<=1.0 -> 0x3F800 < 2^19.
__device__ __forceinline__ uint32_t ev_enc(float ev) {
    return (__float_as_uint(ev) + 0x800u) >> 12;
}
__device__ __forceinline__ float ev_dec(uint32_t q) {
    return __uint_as_float(q << 12);
}

__device__ __forceinline__ void load_pair(const int* __restrict__ cls,
                                          const int* __restrict__ lits,
                                          int base, int c1, int (&cc)[8], int (&ll)[8]) {
    if (base + 8 <= c1) {
        v4i ca = __builtin_nontemporal_load((const v4i*)(cls  + base));
        v4i cb = __builtin_nontemporal_load((const v4i*)(cls  + base + 4));
        v4i la = __builtin_nontemporal_load((const v4i*)(lits + base));
        v4i lb = __builtin_nontemporal_load((const v4i*)(lits + base + 4));
        #pragma unroll
        for (int i = 0; i < 4; ++i) {
            cc[i] = ca[i]; cc[4 + i] = cb[i];
            ll[i] = la[i]; ll[4 + i] = lb[i];
        }
    } else {
        #pragma unroll
        for (int i = 0; i < 8; ++i) {
            int e = base + i;
            if (e < c1) { cc[i] = cls[e]; ll[i] = lits[e]; }
            else        { cc[i] = -1;     ll[i] = 0;       }
        }
    }
}

__device__ __forceinline__ void load_ef(const int* __restrict__ efi,
                                        int base, int c1, int (&ss)[8]) {
    if (base + 8 <= c1) {
        v4i fa = __builtin_nontemporal_load((const v4i*)(efi + base));
        v4i fb = __builtin_nontemporal_load((const v4i*)(efi + base + 4));
        #pragma unroll
        for (int i = 0; i < 4; ++i) { ss[i] = fa[i]; ss[4 + i] = fb[i]; }
    } else {
        #pragma unroll
        for (int i = 0; i < 8; ++i) { int e = base + i; ss[i] = (e < c1) ? efi[e] : 0; }
    }
}

// Phase A: 4-barrier pipelined batches over 489 coarse buckets.
__global__ __launch_bounds__(SC_THREADS, 8) void
scatter_kernel(const float* __restrict__ vp,
               const int* __restrict__ lits,
               const int* __restrict__ cls,
               const int* __restrict__ efi,     // ef as int bits (sign = -1)
               uint32_t* __restrict__ payload,  // [nbp][CAP]
               uint32_t* __restrict__ cursors,  // [NB_TOTAL], zeroed
               int n_edges, int b_lo, int b_hi) {
    __shared__ uint32_t bh[512];          // padded histogram
    __shared__ uint32_t bOff[512];        // exclusive scan of bh (LDS base)
    __shared__ uint32_t bb[512];          // per-batch claimed global base
    __shared__ uint32_t buf[BATCH];       // staged packed entries (32 KB)
    __shared__ uint16_t bufB[BATCH];      // staged bucket ids (16 KB)
    __shared__ uint32_t totalS;

    const int tid  = threadIdx.x;
    const int lane = tid & 63;
    const int wv   = tid >> 6;
    const int nbp  = b_hi - b_lo;         // <= 489
    const int c0   = blockIdx.x * SC_CHUNK;
    const int c1   = min(n_edges, c0 + SC_CHUNK);
    const int nb   = (c1 - c0 + BATCH - 1) / BATCH;   // block-uniform

    // prologue: batch-0 streams in flight while bh zeroes
    int cc[8], ll[8];
    load_pair(cls, lits, c0 + tid * 8, c1, cc, ll);
    if (tid < 512) bh[tid] = 0;
    __syncthreads();

    for (int k = 0; k < nb; ++k) {
        const int base = c0 + k * BATCH + tid * 8;

        // issue ef loads + all 8 vp gathers (overlap rank/scan below)
        int ss[8];
        load_ef(efi, base, c1, ss);
        float vv[8];
        #pragma unroll
        for (int i = 0; i < 8; ++i) vv[i] = (cc[i] >= 0) ? vp[ll[i]] : 0.0f;

        // rank (needs cc only); pack (cl13 | rank10<<13 | ib9<<23)
        uint32_t meta[8];
        #pragma unroll
        for (int i = 0; i < 8; ++i) {
            meta[i] = 0xFF800000u;                 // ib=511 -> invalid
            if (cc[i] >= 0) {
                int b = cc[i] >> BKT_SHIFT;
                if (b >= b_lo && b < b_hi) {
                    uint32_t ib = (uint32_t)(b - b_lo);
                    uint32_t r  = atomicAdd(&bh[ib], 1u);
                    if (r < 1024u)
                        meta[i] = ((uint32_t)cc[i] & 8191u) | (r << 13) | (ib << 23);
                }
            }
        }
        __syncthreads();                           // B1

        if (wv == 0) {
            // single-wave exclusive scan: 8 contiguous elems/lane, two-pass
            const int jb = lane * 8;
            uint32_t t = 0;
            #pragma unroll
            for (int i = 0; i < 8; ++i) t += bh[jb + i];
            uint32_t x = t;
            #pragma unroll
            for (int d = 1; d < 64; d <<= 1) {
                uint32_t n = __shfl_up(x, (unsigned)d, 64);
                if (lane >= d) x += n;
            }
            uint32_t run = x - t;
            #pragma unroll
            for (int i = 0; i < 8; ++i) {
                uint32_t v = bh[jb + i];
                bOff[jb + i] = run;
                run += v;
            }
            if (lane == 63) totalS = x;
        } else {
            // claim global runs concurrently (reads bh only)
            for (int i = tid - 64; i < nbp; i += SC_THREADS - 64) {
                uint32_t v = bh[i];
                bb[i] = v ? atomicAdd(&cursors[b_lo + i], v) : 0u;
            }
        }
        __syncthreads();                           // B2

        // stage into bucket-grouped LDS (ev select: f=+1 -> vp, f=-1 -> 1-vp)
        #pragma unroll
        for (int i = 0; i < 8; ++i) {
            uint32_t ib = meta[i] >> 23;
            if (ib < 511u) {
                float ev = (ss[i] >= 0) ? vv[i] : (1.0f - vv[i]);
                uint32_t s = bOff[ib] + ((meta[i] >> 13) & 1023u);
                buf[s]  = (ev_enc(ev) << BKT_SHIFT) | (meta[i] & 8191u);
                bufB[s] = (uint16_t)ib;
            }
        }
        if (tid < 512) bh[tid] = 0;                // ready for next batch
        if (k + 1 < nb)                            // prefetch next streams
            load_pair(cls, lits, c0 + (k + 1) * BATCH + tid * 8, c1, cc, ll);
        __syncthreads();                           // B3

        // linear coalesced write-out: all lanes store every iteration
        const uint32_t tS = totalS;
        for (uint32_t s = tid; s < tS; s += SC_THREADS) {
            uint32_t ib   = bufB[s];
            uint32_t gpos = bb[ib] + (s - bOff[ib]);
            if (gpos < (uint32_t)CAP)
                payload[(size_t)ib * CAP + gpos] = buf[s];
        }
        __syncthreads();                           // B4
    }
}

// Phase B: TWO blocks per coarse bucket (same-XCD pair via swizzle); each
// filters its 4096-clause half, counting-sorts it in LDS (u32 atomics only),
// then per-thread register accumulation — no fp atomics anywhere.
__global__ __launch_bounds__(PR_THREADS) void
process_kernel(const uint32_t* __restrict__ payload,
               const uint32_t* __restrict__ cursors,
               const float* __restrict__ gstep,
               const float* __restrict__ epsp,
               double* __restrict__ acc,
               int b_lo, int nbp) {
    __shared__ uint32_t offp[SUB_CLS / 2];   // 2 u16 counts per word, 8 KB
    __shared__ uint32_t srt[SRT_CAP];        // 55.3 KB
    __shared__ uint32_t wscan[8];
    __shared__ double   wsum[8];
    const int tid  = threadIdx.x;
    const int lane = tid & 63;
    const int wv   = tid >> 6;

    // swizzle: bid = 16q + r; coarse = q*8 + (r&7), half = r>>3.
    // halves of one coarse bucket land on the SAME XCD (bid%8 equal) -> L2 share.
    const int bid = blockIdx.x;
    const int ibc = (bid >> 4) * 8 + (bid & 7);
    const int half = (bid >> 3) & 1;
    if (ibc >= nbp) return;
    const int b = b_lo + ibc;
    const uint32_t hmask = (uint32_t)half << 12;

    for (int j = tid; j < SUB_CLS / 2; j += PR_THREADS) offp[j] = 0;
    __syncthreads();

    const uint32_t cnt = min(cursors[b], (uint32_t)CAP);
    const uint32_t* pl = payload + (size_t)ibc * CAP;
    const uint32_t nv = cnt >> 2;

    // pass 1: histogram of this half's clauses (packed u16 halves)
    for (uint32_t k = tid; k < nv; k += PR_THREADS) {
        uint4 p4 = ((const uint4*)pl)[k];
        #pragma unroll
        for (int j = 0; j < 4; ++j) {
            uint32_t p = (j == 0) ? p4.x : (j == 1) ? p4.y : (j == 2) ? p4.z : p4.w;
            if ((p & 4096u) == hmask) {
                uint32_t c = p & 4095u;
                atomicAdd(&offp[c >> 1], 1u << ((c & 1) << 4));
            }
        }
    }
    for (uint32_t k = (nv << 2) + tid; k < cnt; k += PR_THREADS) {
        uint32_t p = pl[k];
        if ((p & 4096u) == hmask) {
            uint32_t c = p & 4095u;
            atomicAdd(&offp[c >> 1], 1u << ((c & 1) << 4));
        }
    }
    __syncthreads();

    // in-place exclusive scan of 2048 packed-u16 words (thread owns 4 words)
    uint32_t pk[4];
    const int jb = tid * 4;
    uint32_t t = 0;
    #pragma unroll
    for (int i = 0; i < 4; ++i) {
        pk[i] = offp[jb + i];
        t += (pk[i] & 0xFFFFu) + (pk[i] >> 16);
    }
    uint32_t x = t;
    #pragma unroll
    for (int d = 1; d < 64; d <<= 1) {
        uint32_t n = __shfl_up(x, (unsigned)d, 64);
        if (lane >= d) x += n;
    }
    if (lane == 63) wscan[wv] = x;
    __syncthreads();
    if (tid == 0) {
        uint32_t r = 0;
        #pragma unroll
        for (int w = 0; w < 8; ++w) { uint32_t tm = wscan[w]; wscan[w] = r; r += tm; }
    }
    __syncthreads();
    uint32_t run = (x - t) + wscan[wv];
    #pragma unroll
    for (int i = 0; i < 4; ++i) {
        uint32_t lo = pk[i] & 0xFFFFu, hi = pk[i] >> 16;
        offp[jb + i] = run | ((run + lo) << 16);
        run += lo + hi;
    }
    __syncthreads();

    // pass 2: place this half's entries clause-sorted (ds_add_rtn_u32 rank)
    for (uint32_t k = tid; k < nv; k += PR_THREADS) {
        uint4 p4 = ((const uint4*)pl)[k];
        #pragma unroll
        for (int j = 0; j < 4; ++j) {
            uint32_t p = (j == 0) ? p4.x : (j == 1) ? p4.y : (j == 2) ? p4.z : p4.w;
            if ((p & 4096u) == hmask) {
                uint32_t c = p & 4095u;
                uint32_t sh = (c & 1) << 4;
                uint32_t r = atomicAdd(&offp[c >> 1], 1u << sh);
                uint32_t pos = (r >> sh) & 0xFFFFu;
                if (pos < (uint32_t)SRT_CAP) srt[pos] = p;
            }
        }
    }
    for (uint32_t k = (nv << 2) + tid; k < cnt; k += PR_THREADS) {
        uint32_t p = pl[k];
        if ((p & 4096u) == hmask) {
            uint32_t c = p & 4095u;
            uint32_t sh = (c & 1) << 4;
            uint32_t r = atomicAdd(&offp[c >> 1], 1u << sh);
            uint32_t pos = (r >> sh) & 0xFFFFu;
            if (pos < (uint32_t)SRT_CAP) srt[pos] = p;
        }
    }
    __syncthreads();
    // offp half j == END of segment j; start(j) = end(j-1), start(0)=0

    // pass 3: per-clause register accumulation + log epilogue
    const float coeff = fminf(sqrtf(gstep[0]), 10.0f);
    const float eps   = epsp[0];
    const int gbase = (b << BKT_SHIFT) + (half << 12);
    double local = 0.0;
    for (int j = tid; j < SUB_CLS; j += PR_THREADS) {
        if (gbase + j < N_CLAUSES_C) {
            uint32_t e = (offp[j >> 1] >> ((j & 1) << 4)) & 0xFFFFu;
            uint32_t s = 0;
            if (j > 0) {
                int jm = j - 1;
                s = (offp[jm >> 1] >> ((jm & 1) << 4)) & 0xFFFFu;
            }
            e = min(e, (uint32_t)SRT_CAP);
            s = min(s, e);
            float nom = 0.f, den = 0.f;
            for (uint32_t k = s; k < e; ++k) {
                float ev = ev_dec(srt[k] >> BKT_SHIFT);
                float w  = __expf(coeff * ev);
                nom = fmaf(w, ev, nom);
                den += w;
            }
            float cv = den / fmaxf(nom, eps);   // empty clause: 0/eps = 0 (ref-match)
            float tt = cv - 1.0f;
            float t2 = tt * tt;
            float cv2 = 1.0f + t2 * t2 * tt;    // 1 + (cv-1)^5
            local += (double)__logf(fmaxf(cv2, eps));
        }
    }
    #pragma unroll
    for (int off = 32; off > 0; off >>= 1) local += __shfl_down(local, off, 64);
    if (lane == 0) wsum[wv] = local;
    __syncthreads();
    if (tid == 0) {
        double s = 0.0;
        #pragma unroll
        for (int w = 0; w < 8; ++w) s += wsum[w];
        unsafeAtomicAdd(acc, s);
    }
}

__global__ void finalize_kernel(const double* __restrict__ acc,
                                const int* __restrict__ ncp,
                                float* __restrict__ out) {
    if (threadIdx.x == 0 && blockIdx.x == 0)
        out[0] = (float)(acc[0] / (double)ncp[0]);
}

extern "C" void kernel_launch(void* const* d_in, const int* in_sizes, int n_in,
                              void* d_out, int out_size, void* d_ws, size_t ws_size,
                              hipStream_t stream) {
    const float* vp    = (const float*)d_in[0];
    const int*   gmap  = (const int*)d_in[1];
    const float* ef    = (const float*)d_in[2];
    const int*   ncp   = (const int*)d_in[3];
    const float* gstep = (const float*)d_in[4];
    const float* epsp  = (const float*)d_in[5];
    float*       out   = (float*)d_out;

    const int n_edges = in_sizes[1] / 2;
    const int* lits = gmap;
    const int* cls  = gmap + n_edges;

    // choose pass count so payload fits the workspace (P=1 needs ~50.3MB)
    int P = 8;
    int nbp_max = (NB_TOTAL + 7) / 8;
    size_t cursors_off_w = (size_t)nbp_max * CAP;
    size_t acc_off_w = (cursors_off_w + NB_TOTAL + 1) & ~(size_t)1;
    const int cands[4] = {1, 2, 4, 8};
    for (int ci = 0; ci < 4; ++ci) {
        int cand = cands[ci];
        int nm = (NB_TOTAL + cand - 1) / cand;
        size_t pw = (size_t)nm * CAP;
        size_t cw = pw + NB_TOTAL;
        size_t aw = (cw + 1) & ~(size_t)1;
        size_t need = aw * 4 + 8;
        if (need <= ws_size) { P = cand; nbp_max = nm; cursors_off_w = pw; acc_off_w = aw; break; }
    }

    uint32_t* payload = (uint32_t*)d_ws;
    uint32_t* cursors = payload + cursors_off_w;
    double*   acc     = (double*)((uint32_t*)d_ws + acc_off_w);

    // zero cursors + accumulator every call (ws is poisoned, not re-zeroed)
    hipMemsetAsync(cursors, 0, (acc_off_w - cursors_off_w) * 4 + 8, stream);

    const int sc_blocks = (n_edges + SC_CHUNK - 1) / SC_CHUNK;  // 489 for 12M
    for (int p = 0; p < P; ++p) {
        int b_lo = p * nbp_max;
        int b_hi = min(NB_TOTAL, b_lo + nbp_max);
        if (b_lo >= b_hi) continue;
        int nbp = b_hi - b_lo;
        scatter_kernel<<<sc_blocks, SC_THREADS, 0, stream>>>(
            vp, lits, cls, (const int*)ef, payload, cursors, n_edges, b_lo, b_hi);
        int pr_grid = ((2 * nbp + 15) / 16) * 16;   // swizzle-friendly rounding
        process_kernel<<<pr_grid, PR_THREADS, 0, stream>>>(
            payload, cursors, gstep, epsp, acc, b_lo, nbp);
    }
    finalize_kernel<<<1, 64, 0, stream>>>(acc, ncp, out);
}

// Round 14
// 166.420 us; speedup vs baseline: 1.4370x; 1.0263x over previous
//
#include <hip/hip_runtime.h>
#include <math.h>

// Problem constants: ALPHA=0.5, MAX_COEFF=10, SHARPNESS=5
// N_VARS=1e6, N_CLAUSES=4e6, N_EDGES=12e6

constexpr int   N_CLAUSES_C = 4000000;
constexpr int   BKT_SHIFT   = 13;                                        // 8192 clauses / coarse bucket
constexpr int   BKT_CLS     = 1 << BKT_SHIFT;
constexpr int   NB_TOTAL    = (N_CLAUSES_C + BKT_CLS - 1) >> BKT_SHIFT;  // 489
constexpr int   CAP         = 25728;   // mean 24576, sd ~157; ~7 sigma
constexpr int   SUB_CLS     = 4096;    // process granularity (half a coarse bucket)
constexpr int   SRT_CAP     = 13824;   // sub-bucket mean 12288 + 7 sigma + pad
constexpr int   SC_THREADS  = 1024;
constexpr int   BATCH       = 8192;    // runs ~16.8 words (~67B) with 489 buckets
constexpr int   NBATCH      = 3;
constexpr int   SC_CHUNK    = BATCH * NBATCH;   // 24576 -> 489 blocks
constexpr int   PR_THREADS  = 512;

typedef int v4i __attribute__((ext_vector_type(4)));

// ev encoding: top-19-bits-of-f32 with round-to-nearest. RELATIVE err <= 2^-12
// at every magnitude (linear quant zeroed tiny ev -> cv=den/nom -> inf).
// Exact for 0; monotone; ev<=1.0 -> 0x3F800 < 2^19.
__device__ __forceinline__ uint32_t ev_enc(float ev) {
    return (__float_as_uint(ev) + 0x800u) >> 12;
}
__device__ __forceinline__ float ev_dec(uint32_t q) {
    return __uint_as_float(q << 12);
}

__device__ __forceinline__ void load_pair(const int* __restrict__ cls,
                                          const int* __restrict__ lits,
                                          int base, int c1, int (&cc)[8], int (&ll)[8]) {
    if (base + 8 <= c1) {
        v4i ca = __builtin_nontemporal_load((const v4i*)(cls  + base));
        v4i cb = __builtin_nontemporal_load((const v4i*)(cls  + base + 4));
        v4i la = __builtin_nontemporal_load((const v4i*)(lits + base));
        v4i lb = __builtin_nontemporal_load((const v4i*)(lits + base + 4));
        #pragma unroll
        for (int i = 0; i < 4; ++i) {
            cc[i] = ca[i]; cc[4 + i] = cb[i];
            ll[i] = la[i]; ll[4 + i] = lb[i];
        }
    } else {
        #pragma unroll
        for (int i = 0; i < 8; ++i) {
            int e = base + i;
            if (e < c1) { cc[i] = cls[e]; ll[i] = lits[e]; }
            else        { cc[i] = -1;     ll[i] = 0;       }
        }
    }
}

__device__ __forceinline__ void load_ef(const int* __restrict__ efi,
                                        int base, int c1, int (&ss)[8]) {
    if (base + 8 <= c1) {
        v4i fa = __builtin_nontemporal_load((const v4i*)(efi + base));
        v4i fb = __builtin_nontemporal_load((const v4i*)(efi + base + 4));
        #pragma unroll
        for (int i = 0; i < 4; ++i) { ss[i] = fa[i]; ss[4 + i] = fb[i]; }
    } else {
        #pragma unroll
        for (int i = 0; i < 8; ++i) { int e = base + i; ss[i] = (e < c1) ? efi[e] : 0; }
    }
}

// Phase A: 3-barrier software-pipelined batches.
// steady state per batch k:
//   {wave0: scan bh | waves1-15: claim bb}            -> B
//   {stage(k) from meta/ss/vv; zero bh; prefetch cc}  -> B
//   {issue ef/gathers(k+1); rank(k+1) -> bh,meta  ||  write-out(k)} -> B
// rank touches only bh/cc; write-out touches only buf/bufB/bOff/bb: disjoint.
__global__ __launch_bounds__(SC_THREADS) void
scatter_kernel(const float* __restrict__ vp,
               const int* __restrict__ lits,
               const int* __restrict__ cls,
               const int* __restrict__ efi,     // ef as int bits (sign = -1)
               uint32_t* __restrict__ payload,  // [nbp][CAP]
               uint32_t* __restrict__ cursors,  // [NB_TOTAL], zeroed
               int n_edges, int b_lo, int b_hi) {
    __shared__ uint32_t bh[512];          // padded histogram
    __shared__ uint32_t bOff[512];        // exclusive scan of bh (LDS base)
    __shared__ uint32_t bb[512];          // per-batch claimed global base
    __shared__ uint32_t buf[BATCH];       // staged packed entries (32 KB)
    __shared__ uint16_t bufB[BATCH];      // staged bucket ids (16 KB)
    __shared__ uint32_t totalS;

    const int tid  = threadIdx.x;
    const int lane = tid & 63;
    const int wv   = tid >> 6;
    const int nbp  = b_hi - b_lo;         // <= 489
    const int c0   = blockIdx.x * SC_CHUNK;
    const int c1   = min(n_edges, c0 + SC_CHUNK);
    const int nb   = (c1 - c0 + BATCH - 1) / BATCH;   // block-uniform

    int cc[8], ll[8], ss[8];
    float vv[8];
    uint32_t meta[8];

    // prologue: load batch-0 streams, zero bh
    load_pair(cls, lits, c0 + tid * 8, c1, cc, ll);
    if (tid < 512) bh[tid] = 0;
    __syncthreads();

    // prologue rank(0): issue ef+gathers, rank into bh/meta
    load_ef(efi, c0 + tid * 8, c1, ss);
    #pragma unroll
    for (int i = 0; i < 8; ++i) vv[i] = (cc[i] >= 0) ? vp[ll[i]] : 0.0f;
    #pragma unroll
    for (int i = 0; i < 8; ++i) {
        meta[i] = 0xFF800000u;                 // ib=511 -> invalid
        if (cc[i] >= 0) {
            int b = cc[i] >> BKT_SHIFT;
            if (b >= b_lo && b < b_hi) {
                uint32_t ib = (uint32_t)(b - b_lo);
                uint32_t r  = atomicAdd(&bh[ib], 1u);
                if (r < 1024u)
                    meta[i] = ((uint32_t)cc[i] & 8191u) | (r << 13) | (ib << 23);
            }
        }
    }
    __syncthreads();

    for (int k = 0; k < nb; ++k) {
        // phase S: wave0 scans bh -> bOff/totalS; other waves claim global runs
        if (wv == 0) {
            const int jb = lane * 8;
            uint32_t t = 0;
            #pragma unroll
            for (int i = 0; i < 8; ++i) t += bh[jb + i];
            uint32_t x = t;
            #pragma unroll
            for (int d = 1; d < 64; d <<= 1) {
                uint32_t n = __shfl_up(x, (unsigned)d, 64);
                if (lane >= d) x += n;
            }
            uint32_t run = x - t;
            #pragma unroll
            for (int i = 0; i < 8; ++i) {
                uint32_t v = bh[jb + i];
                bOff[jb + i] = run;
                run += v;
            }
            if (lane == 63) totalS = x;
        } else {
            for (int i = tid - 64; i < nbp; i += SC_THREADS - 64) {
                uint32_t v = bh[i];
                bb[i] = v ? atomicAdd(&cursors[b_lo + i], v) : 0u;
            }
        }
        __syncthreads();                           // B1

        // phase T: stage(k) into bucket-grouped LDS; zero bh; prefetch cc(k+1)
        #pragma unroll
        for (int i = 0; i < 8; ++i) {
            uint32_t ib = meta[i] >> 23;
            if (ib < 511u) {
                float ev = (ss[i] >= 0) ? vv[i] : (1.0f - vv[i]);
                uint32_t s = bOff[ib] + ((meta[i] >> 13) & 1023u);
                buf[s]  = (ev_enc(ev) << BKT_SHIFT) | (meta[i] & 8191u);
                bufB[s] = (uint16_t)ib;
            }
        }
        if (tid < 512) bh[tid] = 0;
        if (k + 1 < nb)
            load_pair(cls, lits, c0 + (k + 1) * BATCH + tid * 8, c1, cc, ll);
        __syncthreads();                           // B2

        // phase W: rank(k+1) (bh/cc only) overlapped with write-out(k)
        if (k + 1 < nb) {
            load_ef(efi, c0 + (k + 1) * BATCH + tid * 8, c1, ss);
            #pragma unroll
            for (int i = 0; i < 8; ++i) vv[i] = (cc[i] >= 0) ? vp[ll[i]] : 0.0f;
            #pragma unroll
            for (int i = 0; i < 8; ++i) {
                meta[i] = 0xFF800000u;
                if (cc[i] >= 0) {
                    int b = cc[i] >> BKT_SHIFT;
                    if (b >= b_lo && b < b_hi) {
                        uint32_t ib = (uint32_t)(b - b_lo);
                        uint32_t r  = atomicAdd(&bh[ib], 1u);
                        if (r < 1024u)
                            meta[i] = ((uint32_t)cc[i] & 8191u) | (r << 13) | (ib << 23);
                    }
                }
            }
        }
        // linear coalesced write-out(k): all lanes store every iteration
        const uint32_t tS = totalS;
        for (uint32_t s = tid; s < tS; s += SC_THREADS) {
            uint32_t ib   = bufB[s];
            uint32_t gpos = bb[ib] + (s - bOff[ib]);
            if (gpos < (uint32_t)CAP)
                payload[(size_t)ib * CAP + gpos] = buf[s];
        }
        __syncthreads();                           // B3
    }
}

// Phase B: TWO blocks per coarse bucket (same-XCD pair via swizzle); each
// filters its 4096-clause half, counting-sorts it in LDS (u32 atomics only),
// then per-thread register accumulation — no fp atomics anywhere.
__global__ __launch_bounds__(PR_THREADS) void
process_kernel(const uint32_t* __restrict__ payload,
               const uint32_t* __restrict__ cursors,
               const float* __restrict__ gstep,
               const float* __restrict__ epsp,
               double* __restrict__ acc,
               int b_lo, int nbp) {
    __shared__ uint32_t offp[SUB_CLS / 2];   // 2 u16 counts per word, 8 KB
    __shared__ uint32_t srt[SRT_CAP];        // 55.3 KB
    __shared__ uint32_t wscan[8];
    __shared__ double   wsum[8];
    const int tid  = threadIdx.x;
    const int lane = tid & 63;
    const int wv   = tid >> 6;

    // swizzle: bid = 16q + r; coarse = q*8 + (r&7), half = r>>3.
    // halves of one coarse bucket land on the SAME XCD (bid%8 equal) -> L2 share.
    const int bid = blockIdx.x;
    const int ibc = (bid >> 4) * 8 + (bid & 7);
    const int half = (bid >> 3) & 1;
    if (ibc >= nbp) return;
    const int b = b_lo + ibc;
    const uint32_t hmask = (uint32_t)half << 12;

    for (int j = tid; j < SUB_CLS / 2; j += PR_THREADS) offp[j] = 0;
    __syncthreads();

    const uint32_t cnt = min(cursors[b], (uint32_t)CAP);
    const uint32_t* pl = payload + (size_t)ibc * CAP;
    const uint32_t nv = cnt >> 2;

    // pass 1: histogram of this half's clauses (packed u16 halves)
    for (uint32_t k = tid; k < nv; k += PR_THREADS) {
        uint4 p4 = ((const uint4*)pl)[k];
        #pragma unroll
        for (int j = 0; j < 4; ++j) {
            uint32_t p = (j == 0) ? p4.x : (j == 1) ? p4.y : (j == 2) ? p4.z : p4.w;
            if ((p & 4096u) == hmask) {
                uint32_t c = p & 4095u;
                atomicAdd(&offp[c >> 1], 1u << ((c & 1) << 4));
            }
        }
    }
    for (uint32_t k = (nv << 2) + tid; k < cnt; k += PR_THREADS) {
        uint32_t p = pl[k];
        if ((p & 4096u) == hmask) {
            uint32_t c = p & 4095u;
            atomicAdd(&offp[c >> 1], 1u << ((c & 1) << 4));
        }
    }
    __syncthreads();

    // in-place exclusive scan of 2048 packed-u16 words (thread owns 4 words)
    uint32_t pk[4];
    const int jb = tid * 4;
    uint32_t t = 0;
    #pragma unroll
    for (int i = 0; i < 4; ++i) {
        pk[i] = offp[jb + i];
        t += (pk[i] & 0xFFFFu) + (pk[i] >> 16);
    }
    uint32_t x = t;
    #pragma unroll
    for (int d = 1; d < 64; d <<= 1) {
        uint32_t n = __shfl_up(x, (unsigned)d, 64);
        if (lane >= d) x += n;
    }
    if (lane == 63) wscan[wv] = x;
    __syncthreads();
    if (tid == 0) {
        uint32_t r = 0;
        #pragma unroll
        for (int w = 0; w < 8; ++w) { uint32_t tm = wscan[w]; wscan[w] = r; r += tm; }
    }
    __syncthreads();
    uint32_t run = (x - t) + wscan[wv];
    #pragma unroll
    for (int i = 0; i < 4; ++i) {
        uint32_t lo = pk[i] & 0xFFFFu, hi = pk[i] >> 16;
        offp[jb + i] = run | ((run + lo) << 16);
        run += lo + hi;
    }
    __syncthreads();

    // pass 2: place this half's entries clause-sorted (ds_add_rtn_u32 rank)
    for (uint32_t k = tid; k < nv; k += PR_THREADS) {
        uint4 p4 = ((const uint4*)pl)[k];
        #pragma unroll
        for (int j = 0; j < 4; ++j) {
            uint32_t p = (j == 0) ? p4.x : (j == 1) ? p4.y : (j == 2) ? p4.z : p4.w;
            if ((p & 4096u) == hmask) {
                uint32_t c = p & 4095u;
                uint32_t sh = (c & 1) << 4;
                uint32_t r = atomicAdd(&offp[c >> 1], 1u << sh);
                uint32_t pos = (r >> sh) & 0xFFFFu;
                if (pos < (uint32_t)SRT_CAP) srt[pos] = p;
            }
        }
    }
    for (uint32_t k = (nv << 2) + tid; k < cnt; k += PR_THREADS) {
        uint32_t p = pl[k];
        if ((p & 4096u) == hmask) {
            uint32_t c = p & 4095u;
            uint32_t sh = (c & 1) << 4;
            uint32_t r = atomicAdd(&offp[c >> 1], 1u << sh);
            uint32_t pos = (r >> sh) & 0xFFFFu;
            if (pos < (uint32_t)SRT_CAP) srt[pos] = p;
        }
    }
    __syncthreads();
    // offp half j == END of segment j; start(j) = end(j-1), start(0)=0

    // pass 3: per-clause register accumulation + log epilogue
    const float coeff = fminf(sqrtf(gstep[0]), 10.0f);
    const float eps   = epsp[0];
    const int gbase = (b << BKT_SHIFT) + (half << 12);
    double local = 0.0;
    for (int j = tid; j < SUB_CLS; j += PR_THREADS) {
        if (gbase + j < N_CLAUSES_C) {
            uint32_t e = (offp[j >> 1] >> ((j & 1) << 4)) & 0xFFFFu;
            uint32_t s = 0;
            if (j > 0) {
                int jm = j - 1;
                s = (offp[jm >> 1] >> ((jm & 1) << 4)) & 0xFFFFu;
            }
            e = min(e, (uint32_t)SRT_CAP);
            s = min(s, e);
            float nom = 0.f, den = 0.f;
            for (uint32_t k = s; k < e; ++k) {
                float ev = ev_dec(srt[k] >> BKT_SHIFT);
                float w  = __expf(coeff * ev);
                nom = fmaf(w, ev, nom);
                den += w;
            }
            float cv = den / fmaxf(nom, eps);   // empty clause: 0/eps = 0 (ref-match)
            float tt = cv - 1.0f;
            float t2 = tt * tt;
            float cv2 = 1.0f + t2 * t2 * tt;    // 1 + (cv-1)^5
            local += (double)__logf(fmaxf(cv2, eps));
        }
    }
    #pragma unroll
    for (int off = 32; off > 0; off >>= 1) local += __shfl_down(local, off, 64);
    if (lane == 0) wsum[wv] = local;
    __syncthreads();
    if (tid == 0) {
        double s = 0.0;
        #pragma unroll
        for (int w = 0; w < 8; ++w) s += wsum[w];
        unsafeAtomicAdd(acc, s);
    }
}

__global__ void finalize_kernel(const double* __restrict__ acc,
                                const int* __restrict__ ncp,
                                float* __restrict__ out) {
    if (threadIdx.x == 0 && blockIdx.x == 0)
        out[0] = (float)(acc[0] / (double)ncp[0]);
}

extern "C" void kernel_launch(void* const* d_in, const int* in_sizes, int n_in,
                              void* d_out, int out_size, void* d_ws, size_t ws_size,
                              hipStream_t stream) {
    const float* vp    = (const float*)d_in[0];
    const int*   gmap  = (const int*)d_in[1];
    const float* ef    = (const float*)d_in[2];
    const int*   ncp   = (const int*)d_in[3];
    const float* gstep = (const float*)d_in[4];
    const float* epsp  = (const float*)d_in[5];
    float*       out   = (float*)d_out;

    const int n_edges = in_sizes[1] / 2;
    const int* lits = gmap;
    const int* cls  = gmap + n_edges;

    // choose pass count so payload fits the workspace (P=1 needs ~50.3MB)
    int P = 8;
    int nbp_max = (NB_TOTAL + 7) / 8;
    size_t cursors_off_w = (size_t)nbp_max * CAP;
    size_t acc_off_w = (cursors_off_w + NB_TOTAL + 1) & ~(size_t)1;
    const int cands[4] = {1, 2, 4, 8};
    for (int ci = 0; ci < 4; ++ci) {
        int cand = cands[ci];
        int nm = (NB_TOTAL + cand - 1) / cand;
        size_t pw = (size_t)nm * CAP;
        size_t cw = pw + NB_TOTAL;
        size_t aw = (cw + 1) & ~(size_t)1;
        size_t need = aw * 4 + 8;
        if (need <= ws_size) { P = cand; nbp_max = nm; cursors_off_w = pw; acc_off_w = aw; break; }
    }

    uint32_t* payload = (uint32_t*)d_ws;
    uint32_t* cursors = payload + cursors_off_w;
    double*   acc     = (double*)((uint32_t*)d_ws + acc_off_w);

    // zero cursors + accumulator every call (ws is poisoned, not re-zeroed)
    hipMemsetAsync(cursors, 0, (acc_off_w - cursors_off_w) * 4 + 8, stream);

    const int sc_blocks = (n_edges + SC_CHUNK - 1) / SC_CHUNK;  // 489 for 12M
    for (int p = 0; p < P; ++p) {
        int b_lo = p * nbp_max;
        int b_hi = min(NB_TOTAL, b_lo + nbp_max);
        if (b_lo >= b_hi) continue;
        int nbp = b_hi - b_lo;
        scatter_kernel<<<sc_blocks, SC_THREADS, 0, stream>>>(
            vp, lits, cls, (const int*)ef, payload, cursors, n_edges, b_lo, b_hi);
        int pr_grid = ((2 * nbp + 15) / 16) * 16;   // swizzle-friendly rounding
        process_kernel<<<pr_grid, PR_THREADS, 0, stream>>>(
            payload, cursors, gstep, epsp, acc, b_lo, nbp);
    }
    finalize_kernel<<<1, 64, 0, stream>>>(acc, ncp, out);
}